// Round 2
// baseline (970.640 us; speedup 1.0000x reference)
//
#include <hip/hip_runtime.h>
#include <hip/hip_bf16.h>

// Problem constants
#define NODES 379
#define NG    128
#define NN    48512          // NODES*NG
#define EE    1552384        // NN*32
#define HID   128
#define INCH  379

// ---------------------------------------------------------------------------
// Edge pass 1: effective edge weight + degree accumulation + dst histogram
// ---------------------------------------------------------------------------
__global__ __launch_bounds__(256) void edge_pass1(
    const int* __restrict__ ei, const float* __restrict__ ewt,
    const float* __restrict__ lew,
    float* __restrict__ ew_eff, float* __restrict__ deg, int* __restrict__ cnt)
{
    int e = blockIdx.x * 256 + threadIdx.x;
    if (e >= EE) return;
    int src = ei[e];
    int dst = ei[EE + e];
    int li = src % NODES;
    int lj = dst % NODES;
    float s = 0.5f * (lew[li * NODES + lj] + lew[lj * NODES + li]);
    float le = 2.0f / (1.0f + expf(-s));
    float w = le * ewt[e];
    ew_eff[e] = w;
    atomicAdd(&deg[dst], w);
    atomicAdd(&cnt[dst], 1);
}

// ---------------------------------------------------------------------------
// dinv = rsqrt(deg + 1)  (in place)
// ---------------------------------------------------------------------------
__global__ __launch_bounds__(256) void dinv_kernel(float* __restrict__ deg)
{
    int n = blockIdx.x * 256 + threadIdx.x;
    if (n >= NN) return;
    deg[n] = rsqrtf(deg[n] + 1.0f);
}

// ---------------------------------------------------------------------------
// Exclusive prefix scan of cnt[NN] -> rowstart[NN+1], copy into wpos.
// Single block, 1024 threads, wave-shuffle scan + cross-wave LDS.
// ---------------------------------------------------------------------------
__global__ __launch_bounds__(1024) void scan_kernel(
    const int* __restrict__ cnt, int* __restrict__ rowstart, int* __restrict__ wpos)
{
    __shared__ int wsum[16];
    __shared__ int wpre[16];
    __shared__ int chunk_total;
    __shared__ int carry;
    int tid = threadIdx.x;
    int lane = tid & 63, wid = tid >> 6;
    if (tid == 0) carry = 0;
    __syncthreads();
    for (int base = 0; base < NN; base += 1024) {
        int i = base + tid;
        int v = (i < NN) ? cnt[i] : 0;
        int incl = v;
        #pragma unroll
        for (int off = 1; off < 64; off <<= 1) {
            int t = __shfl_up(incl, off);
            if (lane >= off) incl += t;
        }
        if (lane == 63) wsum[wid] = incl;
        __syncthreads();
        if (tid == 0) {
            int s = 0;
            #pragma unroll
            for (int w = 0; w < 16; ++w) { wpre[w] = s; s += wsum[w]; }
            chunk_total = s;
        }
        __syncthreads();
        int excl = carry + wpre[wid] + (incl - v);
        if (i < NN) { rowstart[i] = excl; wpos[i] = excl; }
        __syncthreads();              // all carry reads done
        if (tid == 0) carry += chunk_total;
        __syncthreads();              // carry update visible
    }
    if (tid == 0) rowstart[NN] = EE;
}

// ---------------------------------------------------------------------------
// Edge pass 2: scatter edges into dst-sorted CSR with folded norm weight
// ---------------------------------------------------------------------------
__global__ __launch_bounds__(256) void edge_pass2(
    const int* __restrict__ ei, const float* __restrict__ ew_eff,
    const float* __restrict__ dinv, int* __restrict__ wpos,
    int* __restrict__ src_sorted, float* __restrict__ w_sorted)
{
    int e = blockIdx.x * 256 + threadIdx.x;
    if (e >= EE) return;
    int src = ei[e];
    int dst = ei[EE + e];
    float w = dinv[src] * ew_eff[e] * dinv[dst];
    int pos = atomicAdd(&wpos[dst], 1);
    src_sorted[pos] = src;
    w_sorted[pos] = w;
}

// ---------------------------------------------------------------------------
// Concatenate W1|We -> Wcat [INCH, 256]
// ---------------------------------------------------------------------------
__global__ __launch_bounds__(256) void build_wcat(
    const float* __restrict__ W1, const float* __restrict__ We, float* __restrict__ Wcat)
{
    int i = blockIdx.x * 256 + threadIdx.x;
    if (i >= INCH * HID) return;
    int k = i / HID, c = i % HID;
    Wcat[k * 256 + c]       = W1[i];
    Wcat[k * 256 + 128 + c] = We[i];
}

// ---------------------------------------------------------------------------
// Simple tiled f32 GEMM: C[M,Ncols] = A[M,K] @ B[K,Ncols]
// BM=BN=64, BK=16, 256 threads, 4x4 per thread.
// M % 64 == 0, Ncols % 64 == 0 assumed; K arbitrary.
// ---------------------------------------------------------------------------
#define BM 64
#define BN 64
#define BK 16
__global__ __launch_bounds__(256) void sgemm(
    const float* __restrict__ A, int lda,
    const float* __restrict__ B, int ldb,
    float* __restrict__ C, int ldc, int K)
{
    __shared__ float As[BK][BM + 4];
    __shared__ float Bs[BK][BN];
    int tx = threadIdx.x & 15, ty = threadIdx.x >> 4;
    int bm = blockIdx.x * BM, bn = blockIdx.y * BN;
    float acc[4][4] = {};
    for (int k0 = 0; k0 < K; k0 += BK) {
        {   // A tile: 64 rows x 16 k, scalar loads (lda=379 breaks float4 alignment)
            int t = threadIdx.x;
            int row = t >> 2;
            int col = (t & 3) * 4;
            const float* ap = A + (size_t)(bm + row) * lda + (k0 + col);
            float v0 = (k0 + col + 0 < K) ? ap[0] : 0.f;
            float v1 = (k0 + col + 1 < K) ? ap[1] : 0.f;
            float v2 = (k0 + col + 2 < K) ? ap[2] : 0.f;
            float v3 = (k0 + col + 3 < K) ? ap[3] : 0.f;
            As[col + 0][row] = v0;
            As[col + 1][row] = v1;
            As[col + 2][row] = v2;
            As[col + 3][row] = v3;
        }
        {   // B tile: 16 k x 64 cols, float4 (ldb multiple of 4)
            int t = threadIdx.x;
            int krow = t >> 4;
            int col = (t & 15) * 4;
            int gk = k0 + krow;
            float4 v = make_float4(0.f, 0.f, 0.f, 0.f);
            if (gk < K) v = *(const float4*)(B + (size_t)gk * ldb + bn + col);
            *(float4*)&Bs[krow][col] = v;
        }
        __syncthreads();
        #pragma unroll
        for (int kk = 0; kk < BK; ++kk) {
            float a[4], b[4];
            #pragma unroll
            for (int i = 0; i < 4; i++) a[i] = As[kk][ty * 4 + i];
            #pragma unroll
            for (int j = 0; j < 4; j++) b[j] = Bs[kk][tx * 4 + j];
            #pragma unroll
            for (int i = 0; i < 4; i++)
                #pragma unroll
                for (int j = 0; j < 4; j++)
                    acc[i][j] += a[i] * b[j];
        }
        __syncthreads();
    }
    #pragma unroll
    for (int i = 0; i < 4; i++) {
        int row = bm + ty * 4 + i;
        float4 v = make_float4(acc[i][0], acc[i][1], acc[i][2], acc[i][3]);
        *(float4*)(C + (size_t)row * ldc + bn + tx * 4) = v;
    }
}

// ---------------------------------------------------------------------------
// Aggregate conv1 + epilogue:
// h[n,c] = relu(sum_e w*xw1[src,c] + dinv[n]^2*xw1[n,c] + b1[c]) + relu(xe[n,c]+be[c])
// xwcat layout: [NN,256], cols 0..127 = x@W1, 128..255 = x@We
// ---------------------------------------------------------------------------
__global__ __launch_bounds__(128) void aggregate1(
    const float* __restrict__ xwcat, const int* __restrict__ rowstart,
    const int* __restrict__ src_sorted, const float* __restrict__ w_sorted,
    const float* __restrict__ dinv, const float* __restrict__ b1,
    const float* __restrict__ be, float* __restrict__ h)
{
    int n = blockIdx.x;
    int c = threadIdx.x;
    float acc = 0.f;
    int e0 = rowstart[n], e1 = rowstart[n + 1];
    for (int e = e0; e < e1; ++e) {
        int src = src_sorted[e];
        float w = w_sorted[e];
        acc += w * xwcat[(size_t)src * 256 + c];
    }
    float d = dinv[n];
    float conv = acc + d * d * xwcat[(size_t)n * 256 + c] + b1[c];
    float skip = xwcat[(size_t)n * 256 + 128 + c] + be[c];
    h[(size_t)n * HID + c] = fmaxf(conv, 0.f) + fmaxf(skip, 0.f);
}

// ---------------------------------------------------------------------------
// Aggregate conv2 + residual + mean-pool accumulation
// ---------------------------------------------------------------------------
__global__ __launch_bounds__(128) void aggregate2(
    const float* __restrict__ hw2, const int* __restrict__ rowstart,
    const int* __restrict__ src_sorted, const float* __restrict__ w_sorted,
    const float* __restrict__ dinv, const float* __restrict__ b2,
    const float* __restrict__ h, float* __restrict__ pooled)
{
    int n = blockIdx.x;
    int c = threadIdx.x;
    float acc = 0.f;
    int e0 = rowstart[n], e1 = rowstart[n + 1];
    for (int e = e0; e < e1; ++e) {
        int src = src_sorted[e];
        float w = w_sorted[e];
        acc += w * hw2[(size_t)src * HID + c];
    }
    float d = dinv[n];
    float conv = acc + d * d * hw2[(size_t)n * HID + c] + b2[c];
    float out = fmaxf(conv, 0.f) + h[(size_t)n * HID + c];
    atomicAdd(&pooled[(n / NODES) * HID + c], out);
}

// ---------------------------------------------------------------------------
// Final FC: out[g] = (pooled[g,:]/379) @ Wfc + bfc
// ---------------------------------------------------------------------------
__global__ __launch_bounds__(128) void final_fc(
    const float* __restrict__ pooled, const float* __restrict__ Wfc,
    const float* __restrict__ bfc, float* __restrict__ out)
{
    int g = blockIdx.x;
    int t = threadIdx.x;
    float v = pooled[g * HID + t] * Wfc[t];
    #pragma unroll
    for (int off = 32; off > 0; off >>= 1) v += __shfl_down(v, off);
    __shared__ float ws2[2];
    if ((t & 63) == 0) ws2[t >> 6] = v;
    __syncthreads();
    if (t == 0) out[g] = (ws2[0] + ws2[1]) * (1.0f / (float)NODES) + bfc[0];
}

// ---------------------------------------------------------------------------
extern "C" void kernel_launch(void* const* d_in, const int* in_sizes, int n_in,
                              void* d_out, int out_size, void* d_ws, size_t ws_size,
                              hipStream_t stream)
{
    const float* x   = (const float*)d_in[0];
    const int*   ei  = (const int*)d_in[1];
    const float* ewt = (const float*)d_in[2];
    // d_in[3] = batch (unused; batch[n] == n/379)
    const float* lew = (const float*)d_in[4];
    const float* W1  = (const float*)d_in[5];
    const float* b1  = (const float*)d_in[6];
    const float* W2  = (const float*)d_in[7];
    const float* b2  = (const float*)d_in[8];
    const float* We  = (const float*)d_in[9];
    const float* be  = (const float*)d_in[10];
    const float* Wfc = (const float*)d_in[11];
    const float* bfc = (const float*)d_in[12];
    float* outp = (float*)d_out;

    // workspace layout
    char* p = (char*)d_ws;
    auto alloc = [&](size_t bytes) { void* r = (void*)p; p += (bytes + 255) & ~(size_t)255; return r; };
    float* ew_eff     = (float*)alloc((size_t)EE * 4);
    int*   src_sorted = (int*)alloc((size_t)EE * 4);
    float* w_sorted   = (float*)alloc((size_t)EE * 4);
    float* deg_dinv   = (float*)alloc((size_t)NN * 4);
    int*   cnt        = (int*)alloc((size_t)NN * 4);
    int*   rowstart   = (int*)alloc((size_t)(NN + 1) * 4);
    int*   wpos       = (int*)alloc((size_t)NN * 4);
    float* Wcat       = (float*)alloc((size_t)INCH * 256 * 4);
    float* xwcat      = (float*)alloc((size_t)NN * 256 * 4);
    float* h          = (float*)alloc((size_t)NN * HID * 4);
    float* hw2        = (float*)alloc((size_t)NN * HID * 4);
    float* pooled     = (float*)alloc((size_t)NG * HID * 4);

    // zero accumulators (ws is poisoned 0xAA before every launch)
    hipMemsetAsync(deg_dinv, 0, (size_t)NN * 4, stream);
    hipMemsetAsync(cnt, 0, (size_t)NN * 4, stream);
    hipMemsetAsync(pooled, 0, (size_t)NG * HID * 4, stream);

    const int EB = (EE + 255) / 256;     // 6064
    const int NB = (NN + 255) / 256;     // 190

    edge_pass1<<<EB, 256, 0, stream>>>(ei, ewt, lew, ew_eff, deg_dinv, cnt);
    dinv_kernel<<<NB, 256, 0, stream>>>(deg_dinv);
    scan_kernel<<<1, 1024, 0, stream>>>(cnt, rowstart, wpos);
    edge_pass2<<<EB, 256, 0, stream>>>(ei, ew_eff, deg_dinv, wpos, src_sorted, w_sorted);

    build_wcat<<<(INCH * HID + 255) / 256, 256, 0, stream>>>(W1, We, Wcat);

    // GEMM1: xwcat[NN,256] = x[NN,379] @ Wcat[379,256]
    {
        dim3 grid(NN / BM, 256 / BN);
        sgemm<<<grid, 256, 0, stream>>>(x, INCH, Wcat, 256, xwcat, 256, INCH);
    }
    aggregate1<<<NN, 128, 0, stream>>>(xwcat, rowstart, src_sorted, w_sorted,
                                       deg_dinv, b1, be, h);
    // GEMM2: hw2[NN,128] = h[NN,128] @ W2[128,128]
    {
        dim3 grid(NN / BM, HID / BN);
        sgemm<<<grid, 256, 0, stream>>>(h, HID, W2, HID, hw2, HID, HID);
    }
    aggregate2<<<NN, 128, 0, stream>>>(hw2, rowstart, src_sorted, w_sorted,
                                       deg_dinv, b2, h, pooled);
    final_fc<<<NG, 128, 0, stream>>>(pooled, Wfc, bfc, outp);
}

// Round 3
// 929.346 us; speedup vs baseline: 1.0444x; 1.0444x over previous
//
#include <hip/hip_runtime.h>
#include <hip/hip_bf16.h>

// Problem constants
#define NODES 379
#define NG    128
#define NN    48512          // NODES*NG
#define EE    1552384        // NN*32
#define HID   128
#define INCH  379

// ---------------------------------------------------------------------------
// Edge pass 1: effective edge weight + degree accumulation + dst histogram
// ---------------------------------------------------------------------------
__global__ __launch_bounds__(256) void edge_pass1(
    const int* __restrict__ ei, const float* __restrict__ ewt,
    const float* __restrict__ lew,
    float* __restrict__ ew_eff, float* __restrict__ deg, int* __restrict__ cnt)
{
    int e = blockIdx.x * 256 + threadIdx.x;
    if (e >= EE) return;
    int src = ei[e];
    int dst = ei[EE + e];
    int li = src % NODES;
    int lj = dst % NODES;
    float s = 0.5f * (lew[li * NODES + lj] + lew[lj * NODES + li]);
    float le = 2.0f / (1.0f + expf(-s));
    float w = le * ewt[e];
    ew_eff[e] = w;
    atomicAdd(&deg[dst], w);
    atomicAdd(&cnt[dst], 1);
}

// ---------------------------------------------------------------------------
// dinv = rsqrt(deg + 1)  (in place)
// ---------------------------------------------------------------------------
__global__ __launch_bounds__(256) void dinv_kernel(float* __restrict__ deg)
{
    int n = blockIdx.x * 256 + threadIdx.x;
    if (n >= NN) return;
    deg[n] = rsqrtf(deg[n] + 1.0f);
}

// ---------------------------------------------------------------------------
// Exclusive prefix scan of cnt[NN] -> rowstart[NN+1], copy into wpos.
// Single block, 1024 threads x 4 elements (int4), wave-shuffle scan.
// ---------------------------------------------------------------------------
__global__ __launch_bounds__(1024) void scan_kernel(
    const int* __restrict__ cnt, int* __restrict__ rowstart, int* __restrict__ wpos)
{
    __shared__ int wsum[16];
    __shared__ int wpre[16];
    __shared__ int chunk_total;
    __shared__ int carry_s;
    int tid = threadIdx.x;
    int lane = tid & 63, wid = tid >> 6;
    if (tid == 0) carry_s = 0;
    __syncthreads();
    for (int base = 0; base < NN; base += 4096) {
        int i4 = base + tid * 4;
        int4 v = {0, 0, 0, 0};
        if (i4 < NN) v = *(const int4*)(cnt + i4);   // NN % 4 == 0
        int s = v.x + v.y + v.z + v.w;
        int incl = s;
        #pragma unroll
        for (int off = 1; off < 64; off <<= 1) {
            int t = __shfl_up(incl, off);
            if (lane >= off) incl += t;
        }
        if (lane == 63) wsum[wid] = incl;
        __syncthreads();
        if (tid == 0) {
            int acc = 0;
            #pragma unroll
            for (int w = 0; w < 16; ++w) { wpre[w] = acc; acc += wsum[w]; }
            chunk_total = acc;
        }
        __syncthreads();
        int excl = carry_s + wpre[wid] + (incl - s);
        if (i4 < NN) {
            int4 r;
            r.x = excl;
            r.y = r.x + v.x;
            r.z = r.y + v.y;
            r.w = r.z + v.z;
            *(int4*)(rowstart + i4) = r;
            *(int4*)(wpos + i4) = r;
        }
        __syncthreads();              // all carry reads done
        if (tid == 0) carry_s += chunk_total;
        __syncthreads();              // carry update visible
    }
    if (tid == 0) rowstart[NN] = EE;
}

// ---------------------------------------------------------------------------
// Edge pass 2: scatter edges into dst-sorted CSR with folded norm weight
// ---------------------------------------------------------------------------
__global__ __launch_bounds__(256) void edge_pass2(
    const int* __restrict__ ei, const float* __restrict__ ew_eff,
    const float* __restrict__ dinv, int* __restrict__ wpos,
    int* __restrict__ src_sorted, float* __restrict__ w_sorted)
{
    int e = blockIdx.x * 256 + threadIdx.x;
    if (e >= EE) return;
    int src = ei[e];
    int dst = ei[EE + e];
    float w = dinv[src] * ew_eff[e] * dinv[dst];
    int pos = atomicAdd(&wpos[dst], 1);
    src_sorted[pos] = src;
    w_sorted[pos] = w;
}

// ---------------------------------------------------------------------------
// Concatenate W1|We -> Wcat [INCH, 256]
// ---------------------------------------------------------------------------
__global__ __launch_bounds__(256) void build_wcat(
    const float* __restrict__ W1, const float* __restrict__ We, float* __restrict__ Wcat)
{
    int i = blockIdx.x * 256 + threadIdx.x;
    if (i >= INCH * HID) return;
    int k = i / HID, c = i % HID;
    Wcat[k * 256 + c]       = W1[i];
    Wcat[k * 256 + 128 + c] = We[i];
}

// ---------------------------------------------------------------------------
// f32 GEMM: C[M,N] = A[M,K] @ B[K,N], 128x128 tile, BK=16, 256 thr, 8x8/thread
// M % 128 == 0, N % 128 == 0; K arbitrary (zero-padded in LDS).
// ---------------------------------------------------------------------------
#define TBM 128
#define TBN 128
#define TBK 16
__global__ __launch_bounds__(256) void sgemm128(
    const float* __restrict__ A, int lda,
    const float* __restrict__ B, int ldb,
    float* __restrict__ C, int ldc, int K)
{
    __shared__ float As[TBK][TBM + 4];
    __shared__ float Bs[TBK][TBN];
    int tid = threadIdx.x;
    int tx = tid & 15;          // 16 col groups of 8
    int ty = tid >> 4;          // 16 row groups of 8
    int bm = blockIdx.x * TBM, bn = blockIdx.y * TBN;
    float acc[8][8] = {};
    for (int k0 = 0; k0 < K; k0 += TBK) {
        {   // A tile: 128 rows x 16 k; thread: row=tid>>1, k half=(tid&1)*8
            int arow = tid >> 1, ak = (tid & 1) * 8;
            const float* ap = A + (size_t)(bm + arow) * lda + k0 + ak;
            #pragma unroll
            for (int u = 0; u < 8; ++u) {
                float v = (k0 + ak + u < K) ? ap[u] : 0.f;
                As[ak + u][arow] = v;
            }
        }
        {   // B tile: 16 k x 128 cols; thread: krow=tid>>4, col=(tid&15)*8
            int brow = tid >> 4, bcol = (tid & 15) * 8;
            const float* bp = B + (size_t)(k0 + brow) * ldb + bn + bcol;
            float4 bv0 = {0, 0, 0, 0}, bv1 = {0, 0, 0, 0};
            if (k0 + brow < K) {
                bv0 = *(const float4*)bp;
                bv1 = *(const float4*)(bp + 4);
            }
            *(float4*)&Bs[brow][bcol] = bv0;
            *(float4*)&Bs[brow][bcol + 4] = bv1;
        }
        __syncthreads();
        #pragma unroll
        for (int kk = 0; kk < TBK; ++kk) {
            float4 A0 = *(const float4*)&As[kk][ty * 8];
            float4 A1 = *(const float4*)&As[kk][ty * 8 + 4];
            float4 B0 = *(const float4*)&Bs[kk][tx * 8];
            float4 B1 = *(const float4*)&Bs[kk][tx * 8 + 4];
            float a_[8] = {A0.x, A0.y, A0.z, A0.w, A1.x, A1.y, A1.z, A1.w};
            float b_[8] = {B0.x, B0.y, B0.z, B0.w, B1.x, B1.y, B1.z, B1.w};
            #pragma unroll
            for (int i = 0; i < 8; i++)
                #pragma unroll
                for (int j = 0; j < 8; j++)
                    acc[i][j] = fmaf(a_[i], b_[j], acc[i][j]);
        }
        __syncthreads();
    }
    #pragma unroll
    for (int i = 0; i < 8; i++) {
        float* cp = C + (size_t)(bm + ty * 8 + i) * ldc + bn + tx * 8;
        float4 v0 = {acc[i][0], acc[i][1], acc[i][2], acc[i][3]};
        float4 v1 = {acc[i][4], acc[i][5], acc[i][6], acc[i][7]};
        *(float4*)cp = v0;
        *(float4*)(cp + 4) = v1;
    }
}

// ---------------------------------------------------------------------------
// Aggregation v2: 1 wave per node. Lane layout: cg=lane&31 (4 cols via
// float4), half=lane>>5 (edge parity). Edge list loaded coalesced into
// registers, broadcast via shfl; 4-deep unrolled gather for MLP.
// ---------------------------------------------------------------------------
__device__ __forceinline__ void fma4(float4& a, float w, float4 v)
{
    a.x = fmaf(w, v.x, a.x);
    a.y = fmaf(w, v.y, a.y);
    a.z = fmaf(w, v.z, a.z);
    a.w = fmaf(w, v.w, a.w);
}

__global__ __launch_bounds__(256) void aggregate1_v2(
    const float* __restrict__ xwcat, const int* __restrict__ rowstart,
    const int* __restrict__ src_sorted, const float* __restrict__ w_sorted,
    const float* __restrict__ dinv, const float* __restrict__ b1,
    const float* __restrict__ be, float* __restrict__ h)
{
    int lane = threadIdx.x & 63;
    int n = blockIdx.x * 4 + (threadIdx.x >> 6);
    int cg = lane & 31, half = lane >> 5;
    const float4* tb = (const float4*)xwcat;     // row stride 64 float4
    int e0 = rowstart[n], e1 = rowstart[n + 1];
    int cnt = e1 - e0;
    float4 a0 = {0,0,0,0}, a1 = {0,0,0,0}, a2 = {0,0,0,0}, a3 = {0,0,0,0};
    for (int base = 0; base < cnt; base += 64) {
        int me = e0 + base + lane;
        int msrc = (me < e1) ? src_sorted[me] : n;
        float mw  = (me < e1) ? w_sorted[me] : 0.f;
        int chunk = min(64, cnt - base);
        for (int jb = 0; jb < chunk; jb += 8) {
            int j = jb + half;
            int   s0 = __shfl(msrc, j);     float w0 = __shfl(mw, j);
            int   s1 = __shfl(msrc, j + 2); float w1 = __shfl(mw, j + 2);
            int   s2 = __shfl(msrc, j + 4); float w2 = __shfl(mw, j + 4);
            int   s3 = __shfl(msrc, j + 6); float w3 = __shfl(mw, j + 6);
            float4 v0 = tb[(size_t)s0 * 64 + cg];
            float4 v1 = tb[(size_t)s1 * 64 + cg];
            float4 v2 = tb[(size_t)s2 * 64 + cg];
            float4 v3 = tb[(size_t)s3 * 64 + cg];
            fma4(a0, w0, v0);
            fma4(a1, w1, v1);
            fma4(a2, w2, v2);
            fma4(a3, w3, v3);
        }
    }
    float4 acc;
    acc.x = a0.x + a1.x + a2.x + a3.x;
    acc.y = a0.y + a1.y + a2.y + a3.y;
    acc.z = a0.z + a1.z + a2.z + a3.z;
    acc.w = a0.w + a1.w + a2.w + a3.w;
    acc.x += __shfl_xor(acc.x, 32);
    acc.y += __shfl_xor(acc.y, 32);
    acc.z += __shfl_xor(acc.z, 32);
    acc.w += __shfl_xor(acc.w, 32);
    float d = dinv[n];
    float dd = d * d;
    if (half == 0) {
        float4 self = tb[(size_t)n * 64 + cg];
        float4 skip = tb[(size_t)n * 64 + 32 + cg];
        float4 bb1 = ((const float4*)b1)[cg];
        float4 bbe = ((const float4*)be)[cg];
        float4 o;
        o.x = fmaxf(acc.x + dd * self.x + bb1.x, 0.f) + fmaxf(skip.x + bbe.x, 0.f);
        o.y = fmaxf(acc.y + dd * self.y + bb1.y, 0.f) + fmaxf(skip.y + bbe.y, 0.f);
        o.z = fmaxf(acc.z + dd * self.z + bb1.z, 0.f) + fmaxf(skip.z + bbe.z, 0.f);
        o.w = fmaxf(acc.w + dd * self.w + bb1.w, 0.f) + fmaxf(skip.w + bbe.w, 0.f);
        ((float4*)h)[(size_t)n * 32 + cg] = o;
    }
}

__global__ __launch_bounds__(256) void aggregate2_v2(
    const float* __restrict__ hw2, const int* __restrict__ rowstart,
    const int* __restrict__ src_sorted, const float* __restrict__ w_sorted,
    const float* __restrict__ dinv, const float* __restrict__ b2,
    const float* __restrict__ h, float* __restrict__ pooled)
{
    int lane = threadIdx.x & 63;
    int n = blockIdx.x * 4 + (threadIdx.x >> 6);
    int cg = lane & 31, half = lane >> 5;
    const float4* tb = (const float4*)hw2;       // row stride 32 float4
    int e0 = rowstart[n], e1 = rowstart[n + 1];
    int cnt = e1 - e0;
    float4 a0 = {0,0,0,0}, a1 = {0,0,0,0}, a2 = {0,0,0,0}, a3 = {0,0,0,0};
    for (int base = 0; base < cnt; base += 64) {
        int me = e0 + base + lane;
        int msrc = (me < e1) ? src_sorted[me] : n;
        float mw  = (me < e1) ? w_sorted[me] : 0.f;
        int chunk = min(64, cnt - base);
        for (int jb = 0; jb < chunk; jb += 8) {
            int j = jb + half;
            int   s0 = __shfl(msrc, j);     float w0 = __shfl(mw, j);
            int   s1 = __shfl(msrc, j + 2); float w1 = __shfl(mw, j + 2);
            int   s2 = __shfl(msrc, j + 4); float w2 = __shfl(mw, j + 4);
            int   s3 = __shfl(msrc, j + 6); float w3 = __shfl(mw, j + 6);
            float4 v0 = tb[(size_t)s0 * 32 + cg];
            float4 v1 = tb[(size_t)s1 * 32 + cg];
            float4 v2 = tb[(size_t)s2 * 32 + cg];
            float4 v3 = tb[(size_t)s3 * 32 + cg];
            fma4(a0, w0, v0);
            fma4(a1, w1, v1);
            fma4(a2, w2, v2);
            fma4(a3, w3, v3);
        }
    }
    float4 acc;
    acc.x = a0.x + a1.x + a2.x + a3.x;
    acc.y = a0.y + a1.y + a2.y + a3.y;
    acc.z = a0.z + a1.z + a2.z + a3.z;
    acc.w = a0.w + a1.w + a2.w + a3.w;
    acc.x += __shfl_xor(acc.x, 32);
    acc.y += __shfl_xor(acc.y, 32);
    acc.z += __shfl_xor(acc.z, 32);
    acc.w += __shfl_xor(acc.w, 32);
    float d = dinv[n];
    float dd = d * d;
    if (half == 0) {
        float4 self = tb[(size_t)n * 32 + cg];
        float4 res  = ((const float4*)h)[(size_t)n * 32 + cg];
        float4 bb2 = ((const float4*)b2)[cg];
        float4 o;
        o.x = fmaxf(acc.x + dd * self.x + bb2.x, 0.f) + res.x;
        o.y = fmaxf(acc.y + dd * self.y + bb2.y, 0.f) + res.y;
        o.z = fmaxf(acc.z + dd * self.z + bb2.z, 0.f) + res.z;
        o.w = fmaxf(acc.w + dd * self.w + bb2.w, 0.f) + res.w;
        int g = n / NODES;
        float* pp = pooled + g * HID + cg * 4;
        atomicAdd(pp + 0, o.x);
        atomicAdd(pp + 1, o.y);
        atomicAdd(pp + 2, o.z);
        atomicAdd(pp + 3, o.w);
    }
}

// ---------------------------------------------------------------------------
// Final FC: out[g] = (pooled[g,:]/379) @ Wfc + bfc
// ---------------------------------------------------------------------------
__global__ __launch_bounds__(128) void final_fc(
    const float* __restrict__ pooled, const float* __restrict__ Wfc,
    const float* __restrict__ bfc, float* __restrict__ out)
{
    int g = blockIdx.x;
    int t = threadIdx.x;
    float v = pooled[g * HID + t] * Wfc[t];
    #pragma unroll
    for (int off = 32; off > 0; off >>= 1) v += __shfl_down(v, off);
    __shared__ float ws2[2];
    if ((t & 63) == 0) ws2[t >> 6] = v;
    __syncthreads();
    if (t == 0) out[g] = (ws2[0] + ws2[1]) * (1.0f / (float)NODES) + bfc[0];
}

// ---------------------------------------------------------------------------
extern "C" void kernel_launch(void* const* d_in, const int* in_sizes, int n_in,
                              void* d_out, int out_size, void* d_ws, size_t ws_size,
                              hipStream_t stream)
{
    const float* x   = (const float*)d_in[0];
    const int*   ei  = (const int*)d_in[1];
    const float* ewt = (const float*)d_in[2];
    // d_in[3] = batch (unused; batch[n] == n/379)
    const float* lew = (const float*)d_in[4];
    const float* W1  = (const float*)d_in[5];
    const float* b1  = (const float*)d_in[6];
    const float* W2  = (const float*)d_in[7];
    const float* b2  = (const float*)d_in[8];
    const float* We  = (const float*)d_in[9];
    const float* be  = (const float*)d_in[10];
    const float* Wfc = (const float*)d_in[11];
    const float* bfc = (const float*)d_in[12];
    float* outp = (float*)d_out;

    // workspace layout
    char* p = (char*)d_ws;
    auto alloc = [&](size_t bytes) { void* r = (void*)p; p += (bytes + 255) & ~(size_t)255; return r; };
    float* ew_eff     = (float*)alloc((size_t)EE * 4);
    int*   src_sorted = (int*)alloc((size_t)EE * 4);
    float* w_sorted   = (float*)alloc((size_t)EE * 4);
    float* deg_dinv   = (float*)alloc((size_t)NN * 4);
    int*   cnt        = (int*)alloc((size_t)NN * 4);
    int*   rowstart   = (int*)alloc((size_t)(NN + 1) * 4);
    int*   wpos       = (int*)alloc((size_t)NN * 4);
    float* Wcat       = (float*)alloc((size_t)INCH * 256 * 4);
    float* xwcat      = (float*)alloc((size_t)NN * 256 * 4);
    float* h          = (float*)alloc((size_t)NN * HID * 4);
    float* hw2        = (float*)alloc((size_t)NN * HID * 4);
    float* pooled     = (float*)alloc((size_t)NG * HID * 4);

    // zero accumulators (ws is poisoned 0xAA before every launch)
    hipMemsetAsync(deg_dinv, 0, (size_t)NN * 4, stream);
    hipMemsetAsync(cnt, 0, (size_t)NN * 4, stream);
    hipMemsetAsync(pooled, 0, (size_t)NG * HID * 4, stream);

    const int EB = (EE + 255) / 256;     // 6064
    const int NB = (NN + 255) / 256;     // 190

    edge_pass1<<<EB, 256, 0, stream>>>(ei, ewt, lew, ew_eff, deg_dinv, cnt);
    dinv_kernel<<<NB, 256, 0, stream>>>(deg_dinv);
    scan_kernel<<<1, 1024, 0, stream>>>(cnt, rowstart, wpos);
    edge_pass2<<<EB, 256, 0, stream>>>(ei, ew_eff, deg_dinv, wpos, src_sorted, w_sorted);

    build_wcat<<<(INCH * HID + 255) / 256, 256, 0, stream>>>(W1, We, Wcat);

    // GEMM1: xwcat[NN,256] = x[NN,379] @ Wcat[379,256]
    {
        dim3 grid(NN / TBM, 256 / TBN);      // 379 x 2
        sgemm128<<<grid, 256, 0, stream>>>(x, INCH, Wcat, 256, xwcat, 256, INCH);
    }
    aggregate1_v2<<<NN / 4, 256, 0, stream>>>(xwcat, rowstart, src_sorted, w_sorted,
                                              deg_dinv, b1, be, h);
    // GEMM2: hw2[NN,128] = h[NN,128] @ W2[128,128]
    {
        dim3 grid(NN / TBM, HID / TBN);      // 379 x 1
        sgemm128<<<grid, 256, 0, stream>>>(h, HID, W2, HID, hw2, HID, HID);
    }
    aggregate2_v2<<<NN / 4, 256, 0, stream>>>(hw2, rowstart, src_sorted, w_sorted,
                                              deg_dinv, b2, h, pooled);
    final_fc<<<NG, 128, 0, stream>>>(pooled, Wfc, bfc, outp);
}

// Round 4
// 812.668 us; speedup vs baseline: 1.1944x; 1.1436x over previous
//
#include <hip/hip_runtime.h>
#include <hip/hip_bf16.h>

// Problem constants
#define NODES 379
#define NG    128
#define NN    48512          // NODES*NG
#define EE    1552384        // NN*32
#define EPAD  (EE + 8 * NN)  // CSR rows padded to multiple of 8
#define HID   128
#define INCH  379

// ---------------------------------------------------------------------------
// Edge pass 1: effective edge weight + degree accumulation + dst histogram
// ---------------------------------------------------------------------------
__global__ __launch_bounds__(256) void edge_pass1(
    const int* __restrict__ ei, const float* __restrict__ ewt,
    const float* __restrict__ lew,
    float* __restrict__ ew_eff, float* __restrict__ deg, int* __restrict__ cnt)
{
    int e = blockIdx.x * 256 + threadIdx.x;
    if (e >= EE) return;
    int src = ei[e];
    int dst = ei[EE + e];
    int li = src % NODES;
    int lj = dst % NODES;
    float s = 0.5f * (lew[li * NODES + lj] + lew[lj * NODES + li]);
    float le = 2.0f / (1.0f + expf(-s));
    float w = le * ewt[e];
    ew_eff[e] = w;
    atomicAdd(&deg[dst], w);
    atomicAdd(&cnt[dst], 1);
}

// ---------------------------------------------------------------------------
// dinv = rsqrt(deg + 1)  (in place)
// ---------------------------------------------------------------------------
__global__ __launch_bounds__(256) void dinv_kernel(float* __restrict__ deg)
{
    int n = blockIdx.x * 256 + threadIdx.x;
    if (n >= NN) return;
    deg[n] = rsqrtf(deg[n] + 1.0f);
}

// ---------------------------------------------------------------------------
// Exclusive prefix scan of pad8(cnt[NN]) -> rowstart[NN+1] (all multiples of
// 8), copy into wpos. Single block, 1024 threads x 4 elements.
// ---------------------------------------------------------------------------
__global__ __launch_bounds__(1024) void scan_kernel(
    const int* __restrict__ cnt, int* __restrict__ rowstart, int* __restrict__ wpos)
{
    __shared__ int wsum[16];
    __shared__ int wpre[16];
    __shared__ int chunk_total;
    __shared__ int carry_s;
    int tid = threadIdx.x;
    int lane = tid & 63, wid = tid >> 6;
    if (tid == 0) carry_s = 0;
    __syncthreads();
    for (int base = 0; base < NN; base += 4096) {
        int i4 = base + tid * 4;
        int4 v = {0, 0, 0, 0};
        if (i4 < NN) v = *(const int4*)(cnt + i4);   // NN % 4 == 0
        int px = (v.x + 7) & ~7;
        int py = (v.y + 7) & ~7;
        int pz = (v.z + 7) & ~7;
        int pw = (v.w + 7) & ~7;
        int s = px + py + pz + pw;
        int incl = s;
        #pragma unroll
        for (int off = 1; off < 64; off <<= 1) {
            int t = __shfl_up(incl, off);
            if (lane >= off) incl += t;
        }
        if (lane == 63) wsum[wid] = incl;
        __syncthreads();
        if (tid == 0) {
            int acc = 0;
            #pragma unroll
            for (int w = 0; w < 16; ++w) { wpre[w] = acc; acc += wsum[w]; }
            chunk_total = acc;
        }
        __syncthreads();
        int excl = carry_s + wpre[wid] + (incl - s);
        if (i4 < NN) {
            int4 r;
            r.x = excl;
            r.y = r.x + px;
            r.z = r.y + py;
            r.w = r.z + pz;
            *(int4*)(rowstart + i4) = r;
            *(int4*)(wpos + i4) = r;
        }
        __syncthreads();              // all carry reads done
        if (tid == 0) carry_s += chunk_total;
        __syncthreads();              // carry update visible
    }
    if (tid == 0) rowstart[NN] = carry_s;
}

// ---------------------------------------------------------------------------
// Edge pass 2: scatter edges into dst-sorted padded CSR with folded norm
// weight. Pad slots keep w=0/src=0 from the pre-zeroed buffers.
// ---------------------------------------------------------------------------
__global__ __launch_bounds__(256) void edge_pass2(
    const int* __restrict__ ei, const float* __restrict__ ew_eff,
    const float* __restrict__ dinv, int* __restrict__ wpos,
    int* __restrict__ src_sorted, float* __restrict__ w_sorted)
{
    int e = blockIdx.x * 256 + threadIdx.x;
    if (e >= EE) return;
    int src = ei[e];
    int dst = ei[EE + e];
    float w = dinv[src] * ew_eff[e] * dinv[dst];
    int pos = atomicAdd(&wpos[dst], 1);
    src_sorted[pos] = src;
    w_sorted[pos] = w;
}

// ---------------------------------------------------------------------------
// Concatenate W1|We -> Wcat [INCH, 256]
// ---------------------------------------------------------------------------
__global__ __launch_bounds__(256) void build_wcat(
    const float* __restrict__ W1, const float* __restrict__ We, float* __restrict__ Wcat)
{
    int i = blockIdx.x * 256 + threadIdx.x;
    if (i >= INCH * HID) return;
    int k = i / HID, c = i % HID;
    Wcat[k * 256 + c]       = W1[i];
    Wcat[k * 256 + 128 + c] = We[i];
}

// ---------------------------------------------------------------------------
// f32 GEMM: 128x128 tile, BK=16, 256 thr, 8x8/thread. Output column block
// blockIdx.y is written to C0 (y==0) or C1 (y==1), both ldc=128.
// ---------------------------------------------------------------------------
#define TBM 128
#define TBN 128
#define TBK 16
__global__ __launch_bounds__(256) void sgemm128(
    const float* __restrict__ A, int lda,
    const float* __restrict__ B, int ldb,
    float* __restrict__ C0, float* __restrict__ C1, int K)
{
    __shared__ float As[TBK][TBM + 4];
    __shared__ float Bs[TBK][TBN];
    int tid = threadIdx.x;
    int tx = tid & 15;          // 16 col groups of 8
    int ty = tid >> 4;          // 16 row groups of 8
    int bm = blockIdx.x * TBM, bn = blockIdx.y * TBN;
    float acc[8][8] = {};
    for (int k0 = 0; k0 < K; k0 += TBK) {
        {   // A tile: 128 rows x 16 k; thread: row=tid>>1, k half=(tid&1)*8
            int arow = tid >> 1, ak = (tid & 1) * 8;
            const float* ap = A + (size_t)(bm + arow) * lda + k0 + ak;
            #pragma unroll
            for (int u = 0; u < 8; ++u) {
                float v = (k0 + ak + u < K) ? ap[u] : 0.f;
                As[ak + u][arow] = v;
            }
        }
        {   // B tile: 16 k x 128 cols; thread: krow=tid>>4, col=(tid&15)*8
            int brow = tid >> 4, bcol = (tid & 15) * 8;
            const float* bp = B + (size_t)(k0 + brow) * ldb + bn + bcol;
            float4 bv0 = {0, 0, 0, 0}, bv1 = {0, 0, 0, 0};
            if (k0 + brow < K) {
                bv0 = *(const float4*)bp;
                bv1 = *(const float4*)(bp + 4);
            }
            *(float4*)&Bs[brow][bcol] = bv0;
            *(float4*)&Bs[brow][bcol + 4] = bv1;
        }
        __syncthreads();
        #pragma unroll
        for (int kk = 0; kk < TBK; ++kk) {
            float4 A0 = *(const float4*)&As[kk][ty * 8];
            float4 A1 = *(const float4*)&As[kk][ty * 8 + 4];
            float4 B0 = *(const float4*)&Bs[kk][tx * 8];
            float4 B1 = *(const float4*)&Bs[kk][tx * 8 + 4];
            float a_[8] = {A0.x, A0.y, A0.z, A0.w, A1.x, A1.y, A1.z, A1.w};
            float b_[8] = {B0.x, B0.y, B0.z, B0.w, B1.x, B1.y, B1.z, B1.w};
            #pragma unroll
            for (int i = 0; i < 8; i++)
                #pragma unroll
                for (int j = 0; j < 8; j++)
                    acc[i][j] = fmaf(a_[i], b_[j], acc[i][j]);
        }
        __syncthreads();
    }
    float* Cb = (blockIdx.y == 0) ? C0 : C1;
    #pragma unroll
    for (int i = 0; i < 8; i++) {
        float* cp = Cb + (size_t)(bm + ty * 8 + i) * 128 + tx * 8;
        float4 v0 = {acc[i][0], acc[i][1], acc[i][2], acc[i][3]};
        float4 v1 = {acc[i][4], acc[i][5], acc[i][6], acc[i][7]};
        *(float4*)cp = v0;
        *(float4*)(cp + 4) = v1;
    }
}

// ---------------------------------------------------------------------------
// Aggregation v3: block = node (128 threads, thread = column).
// Padded CSR -> aligned int4/float4 edge-meta loads (block-uniform) and
// 8 independent gathers in flight per thread. No shfl, no tail loop.
// ---------------------------------------------------------------------------
__global__ __launch_bounds__(128) void aggregate1_v3(
    const float* __restrict__ xw1, const float* __restrict__ xe,
    const int* __restrict__ rowstart,
    const int* __restrict__ src_sorted, const float* __restrict__ w_sorted,
    const float* __restrict__ dinv, const float* __restrict__ b1,
    const float* __restrict__ be, float* __restrict__ h)
{
    int n = blockIdx.x;
    int c = threadIdx.x;
    int e0 = rowstart[n], e1 = rowstart[n + 1];
    float acc = 0.f;
    for (int e = e0; e < e1; e += 8) {
        int4   sa = *(const int4*)(src_sorted + e);
        int4   sb = *(const int4*)(src_sorted + e + 4);
        float4 wa = *(const float4*)(w_sorted + e);
        float4 wb = *(const float4*)(w_sorted + e + 4);
        float v0 = xw1[(size_t)sa.x * 128 + c];
        float v1 = xw1[(size_t)sa.y * 128 + c];
        float v2 = xw1[(size_t)sa.z * 128 + c];
        float v3 = xw1[(size_t)sa.w * 128 + c];
        float v4 = xw1[(size_t)sb.x * 128 + c];
        float v5 = xw1[(size_t)sb.y * 128 + c];
        float v6 = xw1[(size_t)sb.z * 128 + c];
        float v7 = xw1[(size_t)sb.w * 128 + c];
        acc = fmaf(wa.x, v0, acc);
        acc = fmaf(wa.y, v1, acc);
        acc = fmaf(wa.z, v2, acc);
        acc = fmaf(wa.w, v3, acc);
        acc = fmaf(wb.x, v4, acc);
        acc = fmaf(wb.y, v5, acc);
        acc = fmaf(wb.z, v6, acc);
        acc = fmaf(wb.w, v7, acc);
    }
    float d = dinv[n], dd = d * d;
    float conv = acc + dd * xw1[(size_t)n * 128 + c] + b1[c];
    float skip = xe[(size_t)n * 128 + c] + be[c];
    h[(size_t)n * 128 + c] = fmaxf(conv, 0.f) + fmaxf(skip, 0.f);
}

__global__ __launch_bounds__(128) void aggregate2_v3(
    const float* __restrict__ hw2, const int* __restrict__ rowstart,
    const int* __restrict__ src_sorted, const float* __restrict__ w_sorted,
    const float* __restrict__ dinv, const float* __restrict__ b2,
    const float* __restrict__ h, float* __restrict__ pooled)
{
    int n = blockIdx.x;
    int c = threadIdx.x;
    int e0 = rowstart[n], e1 = rowstart[n + 1];
    float acc = 0.f;
    for (int e = e0; e < e1; e += 8) {
        int4   sa = *(const int4*)(src_sorted + e);
        int4   sb = *(const int4*)(src_sorted + e + 4);
        float4 wa = *(const float4*)(w_sorted + e);
        float4 wb = *(const float4*)(w_sorted + e + 4);
        float v0 = hw2[(size_t)sa.x * 128 + c];
        float v1 = hw2[(size_t)sa.y * 128 + c];
        float v2 = hw2[(size_t)sa.z * 128 + c];
        float v3 = hw2[(size_t)sa.w * 128 + c];
        float v4 = hw2[(size_t)sb.x * 128 + c];
        float v5 = hw2[(size_t)sb.y * 128 + c];
        float v6 = hw2[(size_t)sb.z * 128 + c];
        float v7 = hw2[(size_t)sb.w * 128 + c];
        acc = fmaf(wa.x, v0, acc);
        acc = fmaf(wa.y, v1, acc);
        acc = fmaf(wa.z, v2, acc);
        acc = fmaf(wa.w, v3, acc);
        acc = fmaf(wb.x, v4, acc);
        acc = fmaf(wb.y, v5, acc);
        acc = fmaf(wb.z, v6, acc);
        acc = fmaf(wb.w, v7, acc);
    }
    float d = dinv[n], dd = d * d;
    float conv = acc + dd * hw2[(size_t)n * 128 + c] + b2[c];
    float out = fmaxf(conv, 0.f) + h[(size_t)n * 128 + c];
    atomicAdd(&pooled[(n / NODES) * HID + c], out);
}

// ---------------------------------------------------------------------------
// Final FC: out[g] = (pooled[g,:]/379) @ Wfc + bfc
// ---------------------------------------------------------------------------
__global__ __launch_bounds__(128) void final_fc(
    const float* __restrict__ pooled, const float* __restrict__ Wfc,
    const float* __restrict__ bfc, float* __restrict__ out)
{
    int g = blockIdx.x;
    int t = threadIdx.x;
    float v = pooled[g * HID + t] * Wfc[t];
    #pragma unroll
    for (int off = 32; off > 0; off >>= 1) v += __shfl_down(v, off);
    __shared__ float ws2[2];
    if ((t & 63) == 0) ws2[t >> 6] = v;
    __syncthreads();
    if (t == 0) out[g] = (ws2[0] + ws2[1]) * (1.0f / (float)NODES) + bfc[0];
}

// ---------------------------------------------------------------------------
extern "C" void kernel_launch(void* const* d_in, const int* in_sizes, int n_in,
                              void* d_out, int out_size, void* d_ws, size_t ws_size,
                              hipStream_t stream)
{
    const float* x   = (const float*)d_in[0];
    const int*   ei  = (const int*)d_in[1];
    const float* ewt = (const float*)d_in[2];
    // d_in[3] = batch (unused; batch[n] == n/379)
    const float* lew = (const float*)d_in[4];
    const float* W1  = (const float*)d_in[5];
    const float* b1  = (const float*)d_in[6];
    const float* W2  = (const float*)d_in[7];
    const float* b2  = (const float*)d_in[8];
    const float* We  = (const float*)d_in[9];
    const float* be  = (const float*)d_in[10];
    const float* Wfc = (const float*)d_in[11];
    const float* bfc = (const float*)d_in[12];
    float* outp = (float*)d_out;

    // workspace layout
    char* p = (char*)d_ws;
    auto alloc = [&](size_t bytes) { void* r = (void*)p; p += (bytes + 255) & ~(size_t)255; return r; };
    int*   src_sorted = (int*)alloc((size_t)EPAD * 4);
    float* w_sorted   = (float*)alloc((size_t)EPAD * 4);
    float* deg_dinv   = (float*)alloc((size_t)NN * 4);
    int*   cnt        = (int*)alloc((size_t)NN * 4);
    int*   rowstart   = (int*)alloc((size_t)(NN + 1) * 4);
    int*   wpos       = (int*)alloc((size_t)NN * 4);
    float* Wcat       = (float*)alloc((size_t)INCH * 256 * 4);
    float* xw1        = (float*)alloc((size_t)NN * HID * 4);
    float* xe         = (float*)alloc((size_t)NN * HID * 4);
    float* h          = (float*)alloc((size_t)NN * HID * 4);
    float* hw2        = (float*)alloc((size_t)NN * HID * 4);
    float* pooled     = (float*)alloc((size_t)NG * HID * 4);
    // ew_eff is dead before h is born: alias it onto h's buffer (saves 6 MB)
    float* ew_eff     = h;

    // zero accumulators / padded CSR (ws is poisoned 0xAA before every launch)
    hipMemsetAsync(deg_dinv, 0, (size_t)NN * 4, stream);
    hipMemsetAsync(cnt, 0, (size_t)NN * 4, stream);
    hipMemsetAsync(pooled, 0, (size_t)NG * HID * 4, stream);
    hipMemsetAsync(src_sorted, 0, (size_t)EPAD * 4, stream);
    hipMemsetAsync(w_sorted, 0, (size_t)EPAD * 4, stream);

    const int EB = (EE + 255) / 256;     // 6064
    const int NB = (NN + 255) / 256;     // 190

    edge_pass1<<<EB, 256, 0, stream>>>(ei, ewt, lew, ew_eff, deg_dinv, cnt);
    dinv_kernel<<<NB, 256, 0, stream>>>(deg_dinv);
    scan_kernel<<<1, 1024, 0, stream>>>(cnt, rowstart, wpos);
    edge_pass2<<<EB, 256, 0, stream>>>(ei, ew_eff, deg_dinv, wpos, src_sorted, w_sorted);

    build_wcat<<<(INCH * HID + 255) / 256, 256, 0, stream>>>(W1, We, Wcat);

    // GEMM1: [xw1|xe] = x[NN,379] @ Wcat[379,256]  (split outputs)
    {
        dim3 grid(NN / TBM, 2);              // 379 x 2
        sgemm128<<<grid, 256, 0, stream>>>(x, INCH, Wcat, 256, xw1, xe, INCH);
    }
    aggregate1_v3<<<NN, 128, 0, stream>>>(xw1, xe, rowstart, src_sorted, w_sorted,
                                          deg_dinv, b1, be, h);
    // GEMM2: hw2[NN,128] = h[NN,128] @ W2[128,128]
    {
        dim3 grid(NN / TBM, 1);              // 379 x 1
        sgemm128<<<grid, 256, 0, stream>>>(h, HID, W2, HID, hw2, nullptr, HID);
    }
    aggregate2_v3<<<NN, 128, 0, stream>>>(hw2, rowstart, src_sorted, w_sorted,
                                          deg_dinv, b2, h, pooled);
    final_fc<<<NG, 128, 0, stream>>>(pooled, Wfc, bfc, outp);
}

// Round 5
// 715.688 us; speedup vs baseline: 1.3562x; 1.1355x over previous
//
#include <hip/hip_runtime.h>
#include <hip/hip_bf16.h>

// Problem constants
#define NODES 379
#define NG    128
#define NN    48512          // NODES*NG
#define EE    1552384        // NN*32
#define EPAD  (EE + 8 * NN)  // CSR rows padded to multiple of 8
#define HID   128
#define INCH  379
#define KP1   384            // INCH padded to multiple of 64

typedef __bf16 bf16x8 __attribute__((ext_vector_type(8)));
typedef float  f32x4  __attribute__((ext_vector_type(4)));

__device__ __forceinline__ unsigned short f2bf(float f) {
    __hip_bfloat16 b = __float2bfloat16(f);
    return *reinterpret_cast<unsigned short*>(&b);
}

// ---------------------------------------------------------------------------
// Edge pass 1: effective edge weight + degree accumulation + dst histogram
// ---------------------------------------------------------------------------
__global__ __launch_bounds__(256) void edge_pass1(
    const int* __restrict__ ei, const float* __restrict__ ewt,
    const float* __restrict__ lew,
    float* __restrict__ ew_eff, float* __restrict__ deg, int* __restrict__ cnt)
{
    int e = blockIdx.x * 256 + threadIdx.x;
    if (e >= EE) return;
    int src = ei[e];
    int dst = ei[EE + e];
    int li = src % NODES;
    int lj = dst % NODES;
    float s = 0.5f * (lew[li * NODES + lj] + lew[lj * NODES + li]);
    float le = 2.0f / (1.0f + expf(-s));
    float w = le * ewt[e];
    ew_eff[e] = w;
    atomicAdd(&deg[dst], w);
    atomicAdd(&cnt[dst], 1);
}

// ---------------------------------------------------------------------------
// dinv = rsqrt(deg + 1)  (in place)
// ---------------------------------------------------------------------------
__global__ __launch_bounds__(256) void dinv_kernel(float* __restrict__ deg)
{
    int n = blockIdx.x * 256 + threadIdx.x;
    if (n >= NN) return;
    deg[n] = rsqrtf(deg[n] + 1.0f);
}

// ---------------------------------------------------------------------------
// Exclusive prefix scan of pad8(cnt[NN]) -> rowstart[NN+1] (multiples of 8)
// ---------------------------------------------------------------------------
__global__ __launch_bounds__(1024) void scan_kernel(
    const int* __restrict__ cnt, int* __restrict__ rowstart, int* __restrict__ wpos)
{
    __shared__ int wsum[16];
    __shared__ int wpre[16];
    __shared__ int chunk_total;
    __shared__ int carry_s;
    int tid = threadIdx.x;
    int lane = tid & 63, wid = tid >> 6;
    if (tid == 0) carry_s = 0;
    __syncthreads();
    for (int base = 0; base < NN; base += 4096) {
        int i4 = base + tid * 4;
        int4 v = {0, 0, 0, 0};
        if (i4 < NN) v = *(const int4*)(cnt + i4);   // NN % 4 == 0
        int px = (v.x + 7) & ~7;
        int py = (v.y + 7) & ~7;
        int pz = (v.z + 7) & ~7;
        int pw = (v.w + 7) & ~7;
        int s = px + py + pz + pw;
        int incl = s;
        #pragma unroll
        for (int off = 1; off < 64; off <<= 1) {
            int t = __shfl_up(incl, off);
            if (lane >= off) incl += t;
        }
        if (lane == 63) wsum[wid] = incl;
        __syncthreads();
        if (tid == 0) {
            int acc = 0;
            #pragma unroll
            for (int w = 0; w < 16; ++w) { wpre[w] = acc; acc += wsum[w]; }
            chunk_total = acc;
        }
        __syncthreads();
        int excl = carry_s + wpre[wid] + (incl - s);
        if (i4 < NN) {
            int4 r;
            r.x = excl;
            r.y = r.x + px;
            r.z = r.y + py;
            r.w = r.z + pz;
            *(int4*)(rowstart + i4) = r;
            *(int4*)(wpos + i4) = r;
        }
        __syncthreads();
        if (tid == 0) carry_s += chunk_total;
        __syncthreads();
    }
    if (tid == 0) rowstart[NN] = carry_s;
}

// ---------------------------------------------------------------------------
// Edge pass 2: scatter into dst-sorted padded CSR with folded norm weight
// ---------------------------------------------------------------------------
__global__ __launch_bounds__(256) void edge_pass2(
    const int* __restrict__ ei, const float* __restrict__ ew_eff,
    const float* __restrict__ dinv, int* __restrict__ wpos,
    int* __restrict__ src_sorted, float* __restrict__ w_sorted)
{
    int e = blockIdx.x * 256 + threadIdx.x;
    if (e >= EE) return;
    int src = ei[e];
    int dst = ei[EE + e];
    float w = dinv[src] * ew_eff[e] * dinv[dst];
    int pos = atomicAdd(&wpos[dst], 1);
    src_sorted[pos] = src;
    w_sorted[pos] = w;
}

// ---------------------------------------------------------------------------
// x[NN,379] f32 -> xb[NN,384] bf16 (zero-padded K)
// ---------------------------------------------------------------------------
__global__ __launch_bounds__(256) void convert_x(
    const float* __restrict__ x, unsigned short* __restrict__ xb)
{
    int idx = blockIdx.x * 256 + threadIdx.x;
    if (idx >= NN * 96) return;
    int r = idx / 96, kg = (idx % 96) * 4;
    const float* xp = x + (size_t)r * INCH + kg;
    ushort4 o;
    o.x = (kg + 0 < INCH) ? f2bf(xp[0]) : 0;
    o.y = (kg + 1 < INCH) ? f2bf(xp[1]) : 0;
    o.z = (kg + 2 < INCH) ? f2bf(xp[2]) : 0;
    o.w = (kg + 3 < INCH) ? f2bf(xp[3]) : 0;
    *(ushort4*)(xb + (size_t)r * KP1 + kg) = o;
}

// ---------------------------------------------------------------------------
// Weights: WcatT[256][384] bf16 (row n: col n of [W1|We], K zero-padded),
//          W2T[128][128] bf16 (row n: col n of W2)
// ---------------------------------------------------------------------------
__global__ __launch_bounds__(256) void build_wt(
    const float* __restrict__ W1, const float* __restrict__ We,
    const float* __restrict__ W2,
    unsigned short* __restrict__ WcatT, unsigned short* __restrict__ W2T)
{
    int idx = blockIdx.x * 256 + threadIdx.x;
    if (idx < 256 * KP1) {
        int n = idx / KP1, k = idx % KP1;
        float v = 0.f;
        if (k < INCH) v = (n < 128) ? W1[k * 128 + n] : We[k * 128 + (n - 128)];
        WcatT[idx] = f2bf(v);
    } else {
        int i2 = idx - 256 * KP1;
        if (i2 < 128 * 128) {
            int n = i2 / 128, k = i2 % 128;
            W2T[i2] = f2bf(W2[k * 128 + n]);
        }
    }
}

// ---------------------------------------------------------------------------
// bf16 MFMA GEMM: C[M,N] = A[M,Kp] @ WT[N,Kp]^T
// 128x128 tile, BK=64, 256 thr = 4 waves (2x2 of 64x64 each).
// LDS rows are 128 B -> XOR swizzle byte^=(row&7)<<4 on write AND read (G4).
// Output cols 0..127 -> C0, 128..255 -> C1 (both ldc=128).
// ---------------------------------------------------------------------------
__global__ __launch_bounds__(256) void mfma_gemm(
    const unsigned short* __restrict__ A, int lda,
    const unsigned short* __restrict__ WT, int ldw,
    float* __restrict__ C0, float* __restrict__ C1, int Kp)
{
    __shared__ char lds[32 * 1024];
    char* lA = lds;
    char* lB = lds + 16 * 1024;
    int tid = threadIdx.x;
    int lane = tid & 63, wid = tid >> 6;
    int wr = wid >> 1, wc = wid & 1;
    int l16 = lane & 15, lq = lane >> 4;
    size_t bm = (size_t)blockIdx.x * 128;
    int bn = blockIdx.y * 128;
    f32x4 acc[4][4] = {};

    for (int kb = 0; kb < Kp; kb += 64) {
        {   // stage A tile [128 rows][64 k] and B tile [128 cols][64 k]
            int r = tid >> 1, hk = tid & 1;
            const char* ga = (const char*)(A + (bm + r) * (size_t)lda + kb + hk * 32);
            const char* gb = (const char*)(WT + (size_t)(bn + r) * ldw + kb + hk * 32);
            int rs = (r & 7) << 4;
            #pragma unroll
            for (int i = 0; i < 4; ++i) {
                int4 va = *(const int4*)(ga + i * 16);
                *(int4*)(lA + ((r * 128 + hk * 64 + i * 16) ^ rs)) = va;
            }
            #pragma unroll
            for (int i = 0; i < 4; ++i) {
                int4 vb = *(const int4*)(gb + i * 16);
                *(int4*)(lB + ((r * 128 + hk * 64 + i * 16) ^ rs)) = vb;
            }
        }
        __syncthreads();
        #pragma unroll
        for (int ks = 0; ks < 2; ++ks) {
            int kbyte = ks * 64 + lq * 16;
            bf16x8 af[4], bfr[4];
            #pragma unroll
            for (int mi = 0; mi < 4; ++mi) {
                int r = wr * 64 + mi * 16 + l16;
                af[mi] = *(const bf16x8*)(lA + ((r * 128 + kbyte) ^ ((r & 7) << 4)));
            }
            #pragma unroll
            for (int ni = 0; ni < 4; ++ni) {
                int c = wc * 64 + ni * 16 + l16;
                bfr[ni] = *(const bf16x8*)(lB + ((c * 128 + kbyte) ^ ((c & 7) << 4)));
            }
            #pragma unroll
            for (int mi = 0; mi < 4; ++mi)
                #pragma unroll
                for (int ni = 0; ni < 4; ++ni)
                    acc[mi][ni] = __builtin_amdgcn_mfma_f32_16x16x32_bf16(
                        af[mi], bfr[ni], acc[mi][ni], 0, 0, 0);
        }
        __syncthreads();
    }
    // epilogue: C/D layout col=lane&15, row=(lane>>4)*4+reg
    #pragma unroll
    for (int mi = 0; mi < 4; ++mi) {
        size_t rowbase = bm + wr * 64 + mi * 16 + lq * 4;
        #pragma unroll
        for (int ni = 0; ni < 4; ++ni) {
            int col = bn + wc * 64 + ni * 16 + l16;
            float* Cb = (col < 128) ? (C0 + col) : (C1 + (col - 128));
            #pragma unroll
            for (int j = 0; j < 4; ++j)
                Cb[(rowbase + j) * 128] = acc[mi][ni][j];
        }
    }
}

// ---------------------------------------------------------------------------
// Aggregation v3: block = node (128 threads, thread = column).
// Padded CSR -> aligned int4/float4 edge-meta loads (block-uniform) and
// 8 independent gathers in flight per thread.
// ---------------------------------------------------------------------------
__global__ __launch_bounds__(128) void aggregate1_v3(
    const float* __restrict__ xw1, const float* __restrict__ xe,
    const int* __restrict__ rowstart,
    const int* __restrict__ src_sorted, const float* __restrict__ w_sorted,
    const float* __restrict__ dinv, const float* __restrict__ b1,
    const float* __restrict__ be, float* __restrict__ h,
    unsigned short* __restrict__ hb)
{
    int n = blockIdx.x;
    int c = threadIdx.x;
    int e0 = rowstart[n], e1 = rowstart[n + 1];
    float acc = 0.f;
    for (int e = e0; e < e1; e += 8) {
        int4   sa = *(const int4*)(src_sorted + e);
        int4   sb = *(const int4*)(src_sorted + e + 4);
        float4 wa = *(const float4*)(w_sorted + e);
        float4 wb = *(const float4*)(w_sorted + e + 4);
        float v0 = xw1[(size_t)sa.x * 128 + c];
        float v1 = xw1[(size_t)sa.y * 128 + c];
        float v2 = xw1[(size_t)sa.z * 128 + c];
        float v3 = xw1[(size_t)sa.w * 128 + c];
        float v4 = xw1[(size_t)sb.x * 128 + c];
        float v5 = xw1[(size_t)sb.y * 128 + c];
        float v6 = xw1[(size_t)sb.z * 128 + c];
        float v7 = xw1[(size_t)sb.w * 128 + c];
        acc = fmaf(wa.x, v0, acc);
        acc = fmaf(wa.y, v1, acc);
        acc = fmaf(wa.z, v2, acc);
        acc = fmaf(wa.w, v3, acc);
        acc = fmaf(wb.x, v4, acc);
        acc = fmaf(wb.y, v5, acc);
        acc = fmaf(wb.z, v6, acc);
        acc = fmaf(wb.w, v7, acc);
    }
    float d = dinv[n], dd = d * d;
    float conv = acc + dd * xw1[(size_t)n * 128 + c] + b1[c];
    float skip = xe[(size_t)n * 128 + c] + be[c];
    float out = fmaxf(conv, 0.f) + fmaxf(skip, 0.f);
    h[(size_t)n * 128 + c] = out;
    hb[(size_t)n * 128 + c] = f2bf(out);
}

__global__ __launch_bounds__(128) void aggregate2_v3(
    const float* __restrict__ hw2, const int* __restrict__ rowstart,
    const int* __restrict__ src_sorted, const float* __restrict__ w_sorted,
    const float* __restrict__ dinv, const float* __restrict__ b2,
    const float* __restrict__ h, float* __restrict__ pooled)
{
    int n = blockIdx.x;
    int c = threadIdx.x;
    int e0 = rowstart[n], e1 = rowstart[n + 1];
    float acc = 0.f;
    for (int e = e0; e < e1; e += 8) {
        int4   sa = *(const int4*)(src_sorted + e);
        int4   sb = *(const int4*)(src_sorted + e + 4);
        float4 wa = *(const float4*)(w_sorted + e);
        float4 wb = *(const float4*)(w_sorted + e + 4);
        float v0 = hw2[(size_t)sa.x * 128 + c];
        float v1 = hw2[(size_t)sa.y * 128 + c];
        float v2 = hw2[(size_t)sa.z * 128 + c];
        float v3 = hw2[(size_t)sa.w * 128 + c];
        float v4 = hw2[(size_t)sb.x * 128 + c];
        float v5 = hw2[(size_t)sb.y * 128 + c];
        float v6 = hw2[(size_t)sb.z * 128 + c];
        float v7 = hw2[(size_t)sb.w * 128 + c];
        acc = fmaf(wa.x, v0, acc);
        acc = fmaf(wa.y, v1, acc);
        acc = fmaf(wa.z, v2, acc);
        acc = fmaf(wa.w, v3, acc);
        acc = fmaf(wb.x, v4, acc);
        acc = fmaf(wb.y, v5, acc);
        acc = fmaf(wb.z, v6, acc);
        acc = fmaf(wb.w, v7, acc);
    }
    float d = dinv[n], dd = d * d;
    float conv = acc + dd * hw2[(size_t)n * 128 + c] + b2[c];
    float out = fmaxf(conv, 0.f) + h[(size_t)n * 128 + c];
    atomicAdd(&pooled[(n / NODES) * HID + c], out);
}

// ---------------------------------------------------------------------------
// Final FC: out[g] = (pooled[g,:]/379) @ Wfc + bfc
// ---------------------------------------------------------------------------
__global__ __launch_bounds__(128) void final_fc(
    const float* __restrict__ pooled, const float* __restrict__ Wfc,
    const float* __restrict__ bfc, float* __restrict__ out)
{
    int g = blockIdx.x;
    int t = threadIdx.x;
    float v = pooled[g * HID + t] * Wfc[t];
    #pragma unroll
    for (int off = 32; off > 0; off >>= 1) v += __shfl_down(v, off);
    __shared__ float ws2[2];
    if ((t & 63) == 0) ws2[t >> 6] = v;
    __syncthreads();
    if (t == 0) out[g] = (ws2[0] + ws2[1]) * (1.0f / (float)NODES) + bfc[0];
}

// ---------------------------------------------------------------------------
extern "C" void kernel_launch(void* const* d_in, const int* in_sizes, int n_in,
                              void* d_out, int out_size, void* d_ws, size_t ws_size,
                              hipStream_t stream)
{
    const float* x   = (const float*)d_in[0];
    const int*   ei  = (const int*)d_in[1];
    const float* ewt = (const float*)d_in[2];
    // d_in[3] = batch (unused; batch[n] == n/379)
    const float* lew = (const float*)d_in[4];
    const float* W1  = (const float*)d_in[5];
    const float* b1  = (const float*)d_in[6];
    const float* W2  = (const float*)d_in[7];
    const float* b2  = (const float*)d_in[8];
    const float* We  = (const float*)d_in[9];
    const float* be  = (const float*)d_in[10];
    const float* Wfc = (const float*)d_in[11];
    const float* bfc = (const float*)d_in[12];
    float* outp = (float*)d_out;

    // workspace layout
    char* p = (char*)d_ws;
    auto alloc = [&](size_t bytes) { void* r = (void*)p; p += (bytes + 255) & ~(size_t)255; return r; };
    int*   src_sorted = (int*)alloc((size_t)EPAD * 4);
    float* w_sorted   = (float*)alloc((size_t)EPAD * 4);
    float* deg_dinv   = (float*)alloc((size_t)NN * 4);
    int*   cnt        = (int*)alloc((size_t)NN * 4);
    int*   rowstart   = (int*)alloc((size_t)(NN + 1) * 4);
    int*   wpos       = (int*)alloc((size_t)NN * 4);
    unsigned short* WcatT = (unsigned short*)alloc((size_t)256 * KP1 * 2);
    unsigned short* W2T   = (unsigned short*)alloc((size_t)128 * 128 * 2);
    unsigned short* xb    = (unsigned short*)alloc((size_t)NN * KP1 * 2);
    float* xw1        = (float*)alloc((size_t)NN * HID * 4);
    float* xe         = (float*)alloc((size_t)NN * HID * 4);
    float* h          = (float*)alloc((size_t)NN * HID * 4);
    float* hw2        = (float*)alloc((size_t)NN * HID * 4);
    float* pooled     = (float*)alloc((size_t)NG * HID * 4);
    // aliases (disjoint live ranges):
    float* ew_eff         = h;                    // dead before h is born
    unsigned short* hb    = xb;                   // xb dead after GEMM1

    // zero accumulators / padded CSR
    hipMemsetAsync(deg_dinv, 0, (size_t)NN * 4, stream);
    hipMemsetAsync(cnt, 0, (size_t)NN * 4, stream);
    hipMemsetAsync(pooled, 0, (size_t)NG * HID * 4, stream);
    hipMemsetAsync(src_sorted, 0, (size_t)EPAD * 4, stream);
    hipMemsetAsync(w_sorted, 0, (size_t)EPAD * 4, stream);

    const int EB = (EE + 255) / 256;     // 6064
    const int NB = (NN + 255) / 256;     // 190

    convert_x<<<(NN * 96 + 255) / 256, 256, 0, stream>>>(x, xb);
    build_wt<<<(256 * KP1 + 128 * 128 + 255) / 256, 256, 0, stream>>>(W1, We, W2, WcatT, W2T);

    edge_pass1<<<EB, 256, 0, stream>>>(ei, ewt, lew, ew_eff, deg_dinv, cnt);
    dinv_kernel<<<NB, 256, 0, stream>>>(deg_dinv);
    scan_kernel<<<1, 1024, 0, stream>>>(cnt, rowstart, wpos);
    edge_pass2<<<EB, 256, 0, stream>>>(ei, ew_eff, deg_dinv, wpos, src_sorted, w_sorted);

    // GEMM1: [xw1|xe] = xb[NN,384] @ WcatT^T   (bf16 MFMA)
    {
        dim3 grid(NN / 128, 2);
        mfma_gemm<<<grid, 256, 0, stream>>>(xb, KP1, WcatT, KP1, xw1, xe, KP1);
    }
    aggregate1_v3<<<NN, 128, 0, stream>>>(xw1, xe, rowstart, src_sorted, w_sorted,
                                          deg_dinv, b1, be, h, hb);
    // GEMM2: hw2 = hb[NN,128] @ W2T^T   (bf16 MFMA)
    {
        dim3 grid(NN / 128, 1);
        mfma_gemm<<<grid, 256, 0, stream>>>(hb, 128, W2T, 128, hw2, nullptr, 128);
    }
    aggregate2_v3<<<NN, 128, 0, stream>>>(hw2, rowstart, src_sorted, w_sorted,
                                          deg_dinv, b2, h, pooled);
    final_fc<<<NG, 128, 0, stream>>>(pooled, Wfc, bfc, outp);
}

// Round 6
// 518.773 us; speedup vs baseline: 1.8710x; 1.3796x over previous
//
#include <hip/hip_runtime.h>
#include <hip/hip_bf16.h>

// Problem constants
#define NODES 379
#define NG    128
#define NN    48512          // NODES*NG
#define EE    1552384        // NN*32
#define EPAD  (EE + 8 * NN)  // CSR rows padded to multiple of 8
#define HID   128
#define INCH  379
#define KP1   384            // INCH padded to multiple of 64

typedef __bf16 bf16x8 __attribute__((ext_vector_type(8)));
typedef float  f32x4  __attribute__((ext_vector_type(4)));

__device__ __forceinline__ unsigned short f2bf(float f) {
    __hip_bfloat16 b = __float2bfloat16(f);
    return *reinterpret_cast<unsigned short*>(&b);
}
__device__ __forceinline__ float bflo(unsigned int g) {   // low bf16 -> f32
    return __uint_as_float(g << 16);
}
__device__ __forceinline__ float bfhi(unsigned int g) {   // high bf16 -> f32
    return __uint_as_float(g & 0xffff0000u);
}

// ---------------------------------------------------------------------------
// Edge hist: dst histogram only (1 atomic per edge, 4 edges/thread)
// ---------------------------------------------------------------------------
__global__ __launch_bounds__(256) void edge_hist(
    const int* __restrict__ ei, int* __restrict__ cnt)
{
    int e4 = (blockIdx.x * 256 + threadIdx.x) * 4;
    if (e4 >= EE) return;
    int4 d = *(const int4*)(ei + EE + e4);
    atomicAdd(&cnt[d.x], 1);
    atomicAdd(&cnt[d.y], 1);
    atomicAdd(&cnt[d.z], 1);
    atomicAdd(&cnt[d.w], 1);
}

// ---------------------------------------------------------------------------
// Exclusive prefix scan of pad8(cnt[NN]) -> rowstart[NN+1] (multiples of 8)
// ---------------------------------------------------------------------------
__global__ __launch_bounds__(1024) void scan_kernel(
    const int* __restrict__ cnt, int* __restrict__ rowstart, int* __restrict__ wpos)
{
    __shared__ int wsum[16];
    __shared__ int wpre[16];
    __shared__ int chunk_total;
    __shared__ int carry_s;
    int tid = threadIdx.x;
    int lane = tid & 63, wid = tid >> 6;
    if (tid == 0) carry_s = 0;
    __syncthreads();
    for (int base = 0; base < NN; base += 4096) {
        int i4 = base + tid * 4;
        int4 v = {0, 0, 0, 0};
        if (i4 < NN) v = *(const int4*)(cnt + i4);   // NN % 4 == 0
        int px = (v.x + 7) & ~7;
        int py = (v.y + 7) & ~7;
        int pz = (v.z + 7) & ~7;
        int pw = (v.w + 7) & ~7;
        int s = px + py + pz + pw;
        int incl = s;
        #pragma unroll
        for (int off = 1; off < 64; off <<= 1) {
            int t = __shfl_up(incl, off);
            if (lane >= off) incl += t;
        }
        if (lane == 63) wsum[wid] = incl;
        __syncthreads();
        if (tid == 0) {
            int acc = 0;
            #pragma unroll
            for (int w = 0; w < 16; ++w) { wpre[w] = acc; acc += wsum[w]; }
            chunk_total = acc;
        }
        __syncthreads();
        int excl = carry_s + wpre[wid] + (incl - s);
        if (i4 < NN) {
            int4 r;
            r.x = excl;
            r.y = r.x + px;
            r.z = r.y + py;
            r.w = r.z + pz;
            *(int4*)(rowstart + i4) = r;
            *(int4*)(wpos + i4) = r;
        }
        __syncthreads();
        if (tid == 0) carry_s += chunk_total;
        __syncthreads();
    }
    if (tid == 0) rowstart[NN] = carry_s;
}

// ---------------------------------------------------------------------------
// Edge pass 2: compute effective weight + scatter into dst-sorted padded CSR
// (raw ew, no dinv folding -- dinv is folded into the gather tables)
// ---------------------------------------------------------------------------
__global__ __launch_bounds__(256) void edge_pass2(
    const int* __restrict__ ei, const float* __restrict__ ewt,
    const float* __restrict__ lew, int* __restrict__ wpos,
    int* __restrict__ src_sorted, float* __restrict__ w_sorted)
{
    int e = blockIdx.x * 256 + threadIdx.x;
    if (e >= EE) return;
    int src = ei[e];
    int dst = ei[EE + e];
    int li = src % NODES;
    int lj = dst % NODES;
    float s = 0.5f * (lew[li * NODES + lj] + lew[lj * NODES + li]);
    float le = 2.0f / (1.0f + expf(-s));
    float w = le * ewt[e];
    int pos = atomicAdd(&wpos[dst], 1);
    src_sorted[pos] = src;
    w_sorted[pos] = w;
}

// ---------------------------------------------------------------------------
// deg/dinv from CSR row sums (no atomics): dinv[n] = rsqrt(sum_row(w) + 1)
// ---------------------------------------------------------------------------
__global__ __launch_bounds__(256) void deg_from_csr(
    const int* __restrict__ rowstart, const float* __restrict__ w_sorted,
    float* __restrict__ dinv)
{
    int n = blockIdx.x * 256 + threadIdx.x;
    if (n >= NN) return;
    int e0 = rowstart[n], e1 = rowstart[n + 1];
    float s = 0.f;
    for (int e = e0; e < e1; e += 8) {
        float4 a = *(const float4*)(w_sorted + e);
        float4 b = *(const float4*)(w_sorted + e + 4);
        s += (a.x + a.y) + (a.z + a.w) + ((b.x + b.y) + (b.z + b.w));
    }
    dinv[n] = rsqrtf(s + 1.0f);
}

// ---------------------------------------------------------------------------
// x[NN,379] f32 -> xb[NN,384] bf16 (zero-padded K)
// ---------------------------------------------------------------------------
__global__ __launch_bounds__(256) void convert_x(
    const float* __restrict__ x, unsigned short* __restrict__ xb)
{
    int idx = blockIdx.x * 256 + threadIdx.x;
    if (idx >= NN * 96) return;
    int r = idx / 96, kg = (idx % 96) * 4;
    const float* xp = x + (size_t)r * INCH + kg;
    ushort4 o;
    o.x = (kg + 0 < INCH) ? f2bf(xp[0]) : 0;
    o.y = (kg + 1 < INCH) ? f2bf(xp[1]) : 0;
    o.z = (kg + 2 < INCH) ? f2bf(xp[2]) : 0;
    o.w = (kg + 3 < INCH) ? f2bf(xp[3]) : 0;
    *(ushort4*)(xb + (size_t)r * KP1 + kg) = o;
}

// ---------------------------------------------------------------------------
// Weights: WcatT[256][384] bf16 (row n: col n of [W1|We], K zero-padded),
//          W2T[128][128] bf16 (row n: col n of W2)
// ---------------------------------------------------------------------------
__global__ __launch_bounds__(256) void build_wt(
    const float* __restrict__ W1, const float* __restrict__ We,
    const float* __restrict__ W2,
    unsigned short* __restrict__ WcatT, unsigned short* __restrict__ W2T)
{
    int idx = blockIdx.x * 256 + threadIdx.x;
    if (idx < 256 * KP1) {
        int n = idx / KP1, k = idx % KP1;
        float v = 0.f;
        if (k < INCH) v = (n < 128) ? W1[k * 128 + n] : We[k * 128 + (n - 128)];
        WcatT[idx] = f2bf(v);
    } else {
        int i2 = idx - 256 * KP1;
        if (i2 < 128 * 128) {
            int n = i2 / 128, k = i2 % 128;
            W2T[i2] = f2bf(W2[k * 128 + n]);
        }
    }
}

// ---------------------------------------------------------------------------
// bf16 MFMA GEMM: C = A[M,Kp] @ WT[N,Kp]^T, output bf16.
// 128x128 tile, BK=64, 256 thr = 4 waves (2x2 of 64x64 each).
// LDS rows 128 B -> XOR swizzle byte^=(row&7)<<4 on write AND read (G4).
// Output cols 0..127 -> C0 (scaled by dscale[row]), 128..255 -> C1 (unscaled).
// ---------------------------------------------------------------------------
__global__ __launch_bounds__(256) void mfma_gemm(
    const unsigned short* __restrict__ A, int lda,
    const unsigned short* __restrict__ WT, int ldw,
    unsigned short* __restrict__ C0, unsigned short* __restrict__ C1,
    const float* __restrict__ dscale, int Kp)
{
    __shared__ char lds[32 * 1024];
    char* lA = lds;
    char* lB = lds + 16 * 1024;
    int tid = threadIdx.x;
    int lane = tid & 63, wid = tid >> 6;
    int wr = wid >> 1, wc = wid & 1;
    int l16 = lane & 15, lq = lane >> 4;
    size_t bm = (size_t)blockIdx.x * 128;
    int bn = blockIdx.y * 128;
    f32x4 acc[4][4] = {};

    for (int kb = 0; kb < Kp; kb += 64) {
        {   // stage A tile [128 rows][64 k] and B tile [128 cols][64 k]
            int r = tid >> 1, hk = tid & 1;
            const char* ga = (const char*)(A + (bm + r) * (size_t)lda + kb + hk * 32);
            const char* gb = (const char*)(WT + (size_t)(bn + r) * ldw + kb + hk * 32);
            int rs = (r & 7) << 4;
            #pragma unroll
            for (int i = 0; i < 4; ++i) {
                int4 va = *(const int4*)(ga + i * 16);
                *(int4*)(lA + ((r * 128 + hk * 64 + i * 16) ^ rs)) = va;
            }
            #pragma unroll
            for (int i = 0; i < 4; ++i) {
                int4 vb = *(const int4*)(gb + i * 16);
                *(int4*)(lB + ((r * 128 + hk * 64 + i * 16) ^ rs)) = vb;
            }
        }
        __syncthreads();
        #pragma unroll
        for (int ks = 0; ks < 2; ++ks) {
            int kbyte = ks * 64 + lq * 16;
            bf16x8 af[4], bfr[4];
            #pragma unroll
            for (int mi = 0; mi < 4; ++mi) {
                int r = wr * 64 + mi * 16 + l16;
                af[mi] = *(const bf16x8*)(lA + ((r * 128 + kbyte) ^ ((r & 7) << 4)));
            }
            #pragma unroll
            for (int ni = 0; ni < 4; ++ni) {
                int c = wc * 64 + ni * 16 + l16;
                bfr[ni] = *(const bf16x8*)(lB + ((c * 128 + kbyte) ^ ((c & 7) << 4)));
            }
            #pragma unroll
            for (int mi = 0; mi < 4; ++mi)
                #pragma unroll
                for (int ni = 0; ni < 4; ++ni)
                    acc[mi][ni] = __builtin_amdgcn_mfma_f32_16x16x32_bf16(
                        af[mi], bfr[ni], acc[mi][ni], 0, 0, 0);
        }
        __syncthreads();
    }
    // epilogue: C/D layout col=lane&15, row=(lane>>4)*4+reg
    #pragma unroll
    for (int mi = 0; mi < 4; ++mi) {
        size_t rowbase = bm + wr * 64 + mi * 16 + lq * 4;
        float dsc[4];
        #pragma unroll
        for (int j = 0; j < 4; ++j) dsc[j] = dscale[rowbase + j];
        #pragma unroll
        for (int ni = 0; ni < 4; ++ni) {
            int col = bn + wc * 64 + ni * 16 + l16;
            bool toC0 = (col < 128);
            unsigned short* Cb = toC0 ? C0 : C1;
            int cc = toC0 ? col : (col - 128);
            #pragma unroll
            for (int j = 0; j < 4; ++j) {
                float v = acc[mi][ni][j];
                if (toC0) v *= dsc[j];
                Cb[(rowbase + j) * 128 + cc] = f2bf(v);
            }
        }
    }
}

// ---------------------------------------------------------------------------
// Aggregation v4: 1 wave per node (2 nodes per 128-thread block).
// Lane owns 2 adjacent columns via one uint (2xbf16) gather per edge.
// Tables are pre-scaled by dinv: T[m] = dinv[m]*xw[m], so
//   conv[n] = dinv[n]*(sum_e ew_e*T[src] + T[n]) + bias
// ---------------------------------------------------------------------------
__global__ __launch_bounds__(128) void aggregate1_v4(
    const unsigned short* __restrict__ t1, const unsigned short* __restrict__ xeb,
    const int* __restrict__ rowstart,
    const int* __restrict__ src_sorted, const float* __restrict__ w_sorted,
    const float* __restrict__ dinv, const float* __restrict__ b1,
    const float* __restrict__ be, float* __restrict__ h,
    unsigned short* __restrict__ hb)
{
    int lane = threadIdx.x & 63;
    int n = blockIdx.x * 2 + (threadIdx.x >> 6);
    int co = lane << 1;                       // byte offset = 2 ushorts
    int e0 = rowstart[n], e1 = rowstart[n + 1];
    float aL = 0.f, aH = 0.f;
    for (int e = e0; e < e1; e += 8) {
        int4   sa = *(const int4*)(src_sorted + e);
        int4   sb = *(const int4*)(src_sorted + e + 4);
        float4 wa = *(const float4*)(w_sorted + e);
        float4 wb = *(const float4*)(w_sorted + e + 4);
        unsigned int g0 = *(const unsigned int*)(t1 + (size_t)sa.x * 128 + co);
        unsigned int g1 = *(const unsigned int*)(t1 + (size_t)sa.y * 128 + co);
        unsigned int g2 = *(const unsigned int*)(t1 + (size_t)sa.z * 128 + co);
        unsigned int g3 = *(const unsigned int*)(t1 + (size_t)sa.w * 128 + co);
        unsigned int g4 = *(const unsigned int*)(t1 + (size_t)sb.x * 128 + co);
        unsigned int g5 = *(const unsigned int*)(t1 + (size_t)sb.y * 128 + co);
        unsigned int g6 = *(const unsigned int*)(t1 + (size_t)sb.z * 128 + co);
        unsigned int g7 = *(const unsigned int*)(t1 + (size_t)sb.w * 128 + co);
        aL = fmaf(wa.x, bflo(g0), aL); aH = fmaf(wa.x, bfhi(g0), aH);
        aL = fmaf(wa.y, bflo(g1), aL); aH = fmaf(wa.y, bfhi(g1), aH);
        aL = fmaf(wa.z, bflo(g2), aL); aH = fmaf(wa.z, bfhi(g2), aH);
        aL = fmaf(wa.w, bflo(g3), aL); aH = fmaf(wa.w, bfhi(g3), aH);
        aL = fmaf(wb.x, bflo(g4), aL); aH = fmaf(wb.x, bfhi(g4), aH);
        aL = fmaf(wb.y, bflo(g5), aL); aH = fmaf(wb.y, bfhi(g5), aH);
        aL = fmaf(wb.z, bflo(g6), aL); aH = fmaf(wb.z, bfhi(g6), aH);
        aL = fmaf(wb.w, bflo(g7), aL); aH = fmaf(wb.w, bfhi(g7), aH);
    }
    unsigned int tn  = *(const unsigned int*)(t1 + (size_t)n * 128 + co);
    unsigned int xen = *(const unsigned int*)(xeb + (size_t)n * 128 + co);
    float d = dinv[n];
    float2 bb1 = *(const float2*)(b1 + co);
    float2 bbe = *(const float2*)(be + co);
    float convL = fmaf(d, aL + bflo(tn), bb1.x);
    float convH = fmaf(d, aH + bfhi(tn), bb1.y);
    float skipL = bflo(xen) + bbe.x;
    float skipH = bfhi(xen) + bbe.y;
    float oL = fmaxf(convL, 0.f) + fmaxf(skipL, 0.f);
    float oH = fmaxf(convH, 0.f) + fmaxf(skipH, 0.f);
    *(float2*)(h + (size_t)n * 128 + co) = make_float2(oL, oH);
    unsigned int packed = (unsigned int)f2bf(oL) | ((unsigned int)f2bf(oH) << 16);
    *(unsigned int*)(hb + (size_t)n * 128 + co) = packed;
}

__global__ __launch_bounds__(128) void aggregate2_v4(
    const unsigned short* __restrict__ t2, const int* __restrict__ rowstart,
    const int* __restrict__ src_sorted, const float* __restrict__ w_sorted,
    const float* __restrict__ dinv, const float* __restrict__ b2,
    const float* __restrict__ h, float* __restrict__ out_buf)
{
    int lane = threadIdx.x & 63;
    int n = blockIdx.x * 2 + (threadIdx.x >> 6);
    int co = lane << 1;
    int e0 = rowstart[n], e1 = rowstart[n + 1];
    float aL = 0.f, aH = 0.f;
    for (int e = e0; e < e1; e += 8) {
        int4   sa = *(const int4*)(src_sorted + e);
        int4   sb = *(const int4*)(src_sorted + e + 4);
        float4 wa = *(const float4*)(w_sorted + e);
        float4 wb = *(const float4*)(w_sorted + e + 4);
        unsigned int g0 = *(const unsigned int*)(t2 + (size_t)sa.x * 128 + co);
        unsigned int g1 = *(const unsigned int*)(t2 + (size_t)sa.y * 128 + co);
        unsigned int g2 = *(const unsigned int*)(t2 + (size_t)sa.z * 128 + co);
        unsigned int g3 = *(const unsigned int*)(t2 + (size_t)sa.w * 128 + co);
        unsigned int g4 = *(const unsigned int*)(t2 + (size_t)sb.x * 128 + co);
        unsigned int g5 = *(const unsigned int*)(t2 + (size_t)sb.y * 128 + co);
        unsigned int g6 = *(const unsigned int*)(t2 + (size_t)sb.z * 128 + co);
        unsigned int g7 = *(const unsigned int*)(t2 + (size_t)sb.w * 128 + co);
        aL = fmaf(wa.x, bflo(g0), aL); aH = fmaf(wa.x, bfhi(g0), aH);
        aL = fmaf(wa.y, bflo(g1), aL); aH = fmaf(wa.y, bfhi(g1), aH);
        aL = fmaf(wa.z, bflo(g2), aL); aH = fmaf(wa.z, bfhi(g2), aH);
        aL = fmaf(wa.w, bflo(g3), aL); aH = fmaf(wa.w, bfhi(g3), aH);
        aL = fmaf(wb.x, bflo(g4), aL); aH = fmaf(wb.x, bfhi(g4), aH);
        aL = fmaf(wb.y, bflo(g5), aL); aH = fmaf(wb.y, bfhi(g5), aH);
        aL = fmaf(wb.z, bflo(g6), aL); aH = fmaf(wb.z, bfhi(g6), aH);
        aL = fmaf(wb.w, bflo(g7), aL); aH = fmaf(wb.w, bfhi(g7), aH);
    }
    unsigned int tn = *(const unsigned int*)(t2 + (size_t)n * 128 + co);
    float d = dinv[n];
    float2 bb2 = *(const float2*)(b2 + co);
    float2 hres = *(const float2*)(h + (size_t)n * 128 + co);
    float oL = fmaxf(fmaf(d, aL + bflo(tn), bb2.x), 0.f) + hres.x;
    float oH = fmaxf(fmaf(d, aH + bfhi(tn), bb2.y), 0.f) + hres.y;
    *(float2*)(out_buf + (size_t)n * 128 + co) = make_float2(oL, oH);
}

// ---------------------------------------------------------------------------
// pool + FC fused: out[g] = (1/379)*sum_{i,c} out_buf[g*379+i, c]*Wfc[c] + bfc
// block = 512 threads: c = t&127, row-quarter q = t>>7
// ---------------------------------------------------------------------------
__global__ __launch_bounds__(512) void pool_fc(
    const float* __restrict__ out_buf, const float* __restrict__ Wfc,
    const float* __restrict__ bfc, float* __restrict__ out)
{
    int g = blockIdx.x;
    int t = threadIdx.x;
    int c = t & 127, q = t >> 7;
    const float* p = out_buf + ((size_t)g * NODES + q) * 128 + c;
    float s = 0.f;
    for (int i = q; i < NODES; i += 4) {
        s += *p;
        p += 4 * 128;
    }
    float v = s * Wfc[c];
    #pragma unroll
    for (int off = 32; off > 0; off >>= 1) v += __shfl_down(v, off);
    __shared__ float ws8[8];
    if ((t & 63) == 0) ws8[t >> 6] = v;
    __syncthreads();
    if (t == 0) {
        float tot = 0.f;
        #pragma unroll
        for (int k = 0; k < 8; ++k) tot += ws8[k];
        out[g] = tot * (1.0f / (float)NODES) + bfc[0];
    }
}

// ---------------------------------------------------------------------------
extern "C" void kernel_launch(void* const* d_in, const int* in_sizes, int n_in,
                              void* d_out, int out_size, void* d_ws, size_t ws_size,
                              hipStream_t stream)
{
    const float* x   = (const float*)d_in[0];
    const int*   ei  = (const int*)d_in[1];
    const float* ewt = (const float*)d_in[2];
    // d_in[3] = batch (unused; batch[n] == n/379)
    const float* lew = (const float*)d_in[4];
    const float* W1  = (const float*)d_in[5];
    const float* b1  = (const float*)d_in[6];
    const float* W2  = (const float*)d_in[7];
    const float* b2  = (const float*)d_in[8];
    const float* We  = (const float*)d_in[9];
    const float* be  = (const float*)d_in[10];
    const float* Wfc = (const float*)d_in[11];
    const float* bfc = (const float*)d_in[12];
    float* outp = (float*)d_out;

    // workspace layout
    char* p = (char*)d_ws;
    auto alloc = [&](size_t bytes) { void* r = (void*)p; p += (bytes + 255) & ~(size_t)255; return r; };
    int*   src_sorted = (int*)alloc((size_t)EPAD * 4);
    float* w_sorted   = (float*)alloc((size_t)EPAD * 4);
    int*   cnt        = (int*)alloc((size_t)NN * 4);
    int*   rowstart   = (int*)alloc((size_t)(NN + 1) * 4);
    int*   wpos       = (int*)alloc((size_t)NN * 4);
    float* dinv       = (float*)alloc((size_t)NN * 4);
    unsigned short* WcatT = (unsigned short*)alloc((size_t)256 * KP1 * 2);
    unsigned short* W2T   = (unsigned short*)alloc((size_t)128 * 128 * 2);
    unsigned short* xb    = (unsigned short*)alloc((size_t)NN * KP1 * 2);
    unsigned short* xw1b  = (unsigned short*)alloc((size_t)NN * HID * 2);
    unsigned short* xeb   = (unsigned short*)alloc((size_t)NN * HID * 2);
    unsigned short* hw2b  = (unsigned short*)alloc((size_t)NN * HID * 2);
    float* h          = (float*)alloc((size_t)NN * HID * 4);
    float* out_buf    = (float*)alloc((size_t)NN * HID * 4);
    // alias (disjoint live ranges): xb dead after GEMM1; hb born in aggregate1
    unsigned short* hb = xb;

    // zero histogram + padded CSR (ws is poisoned 0xAA before every launch)
    hipMemsetAsync(cnt, 0, (size_t)NN * 4, stream);
    hipMemsetAsync(src_sorted, 0, (size_t)EPAD * 4, stream);
    hipMemsetAsync(w_sorted, 0, (size_t)EPAD * 4, stream);

    const int EB = (EE + 255) / 256;     // 6064
    const int NB = (NN + 255) / 256;     // 190

    convert_x<<<(NN * 96 + 255) / 256, 256, 0, stream>>>(x, xb);
    build_wt<<<(256 * KP1 + 128 * 128 + 255) / 256, 256, 0, stream>>>(W1, We, W2, WcatT, W2T);

    edge_hist<<<(EE / 4 + 255) / 256, 256, 0, stream>>>(ei, cnt);
    scan_kernel<<<1, 1024, 0, stream>>>(cnt, rowstart, wpos);
    edge_pass2<<<EB, 256, 0, stream>>>(ei, ewt, lew, wpos, src_sorted, w_sorted);
    deg_from_csr<<<NB, 256, 0, stream>>>(rowstart, w_sorted, dinv);

    // GEMM1: xw1b = dinv*(xb@W1) bf16 ; xeb = xb@We bf16
    {
        dim3 grid(NN / 128, 2);
        mfma_gemm<<<grid, 256, 0, stream>>>(xb, KP1, WcatT, KP1, xw1b, xeb, dinv, KP1);
    }
    aggregate1_v4<<<NN / 2, 128, 0, stream>>>(xw1b, xeb, rowstart, src_sorted, w_sorted,
                                              dinv, b1, be, h, hb);
    // GEMM2: hw2b = dinv*(hb@W2) bf16
    {
        dim3 grid(NN / 128, 1);
        mfma_gemm<<<grid, 256, 0, stream>>>(hb, 128, W2T, 128, hw2b, nullptr, dinv, 128);
    }
    aggregate2_v4<<<NN / 2, 128, 0, stream>>>(hw2b, rowstart, src_sorted, w_sorted,
                                              dinv, b2, h, out_buf);
    pool_fc<<<NG, 512, 0, stream>>>(out_buf, Wfc, bfc, outp);
}